// Round 6
// baseline (362.469 us; speedup 1.0000x reference)
//
#include <hip/hip_runtime.h>
#include <hip/hip_bf16.h>
#include <math.h>

#define TN 201
#define NSTEP 200
#define BATCH 4096
#define DIM 20
#define HID 128

typedef __attribute__((ext_vector_type(8))) short short8;
typedef __attribute__((ext_vector_type(4))) float f32x4;

union S8U { short8 s; unsigned u[4]; };

__device__ __forceinline__ unsigned pk2(float lo, float hi) {
  __hip_bfloat162 h = __float22bfloat162_rn(make_float2(lo, hi));
  union { __hip_bfloat162 h; unsigned u; } v;
  v.h = h;
  return v.u;
}
__device__ __forceinline__ float tanh_fast(float x) {
  float e = __builtin_amdgcn_exp2f(x * 2.8853900817779268f);
  return 1.f - 2.f * __builtin_amdgcn_rcpf(e + 1.f);
}

// ws layout (floats):
//   [0..399]       Pp  = sigma^T P
//   [400..799]     Mp  = -sigma^T A sigma^{-T}
//   [800..1199]    Qp  = sigma^T Q
//   [1200..1399]   dt[200]
//   [1400..1599]   1/sqrt(dt)[200]
//   [1600..1631]   b2p = sigma^T b2 (padded to 32)
//   [2048..4607]   W2p = W2 sigma  [128][20]
//   [5120..7167]   W1F table: 8 frags x 64 lanes x 4 dw (prepacked bf16 pairs)
//   [7168..9215]   W2F table: 8 frags x 64 lanes x 4 dw
//   [9216..9727]   PpF table: 2 frags x 64 lanes x 4 dw (TX-frag B: t-col zero, x->Pp)
//   [9728..10239]  MpF table: 2 frags x 64 lanes x 4 dw (Y-frag B: y->Mp, pad zero)
//   [10240..10751] B1  table: [nt 0..7][lane 0..63]
//   [12288 ...]    zc: A1[nch][81920], A2[nch][81920], S[nch][81920]

// ================= k0: setup =================
__global__ __launch_bounds__(256) void k0_setup(
    const float* __restrict__ ts, const float* __restrict__ sigma,
    const float* __restrict__ A, const float* __restrict__ P,
    const float* __restrict__ Q, const float* __restrict__ W2,
    const float* __restrict__ b2, const float* __restrict__ W1,
    const float* __restrict__ b1, float* __restrict__ wsc) {
  __shared__ float aug[20][40];
  __shared__ float sS[400], sA[400], sT1[400];
  __shared__ float fac[20];
  int tid = threadIdx.x;
  for (int e = tid; e < 400; e += 256) { sS[e] = sigma[e]; sA[e] = A[e]; }
  for (int e = tid; e < 800; e += 256) {
    int i = e / 40, j = e % 40;
    aug[i][j] = (j < 20) ? sigma[i * 20 + j] : ((j - 20) == i ? 1.f : 0.f);
  }
  __syncthreads();
  for (int p = 0; p < 20; ++p) {
    // wave 0: scale pivot row + capture fac column (reads before writes,
    // wave-lockstep => safe without extra barrier)
    if (tid < 64) {
      float pv = aug[p][p];
      float r = 1.f / pv;
      float rowv = 0.f, facv = 0.f;
      if (tid < 40) rowv = aug[p][tid];
      if (tid >= 40 && tid < 60) facv = aug[tid - 40][p];
      if (tid < 40) aug[p][tid] = rowv * r;
      if (tid >= 40 && tid < 60) fac[tid - 40] = facv;
    }
    __syncthreads();
    for (int e = tid; e < 800; e += 256) {
      int i = e / 40, j = e % 40;
      if (i != p) aug[i][j] -= fac[i] * aug[p][j];
    }
    __syncthreads();
  }
  // T1[k][j] = (A sigma^{-T})[k][j]
  for (int e = tid; e < 400; e += 256) {
    int k = e / 20, j = e % 20;
    float s = 0.f;
    for (int l2 = 0; l2 < 20; ++l2) s += sA[k * 20 + l2] * aug[j][20 + l2];
    sT1[e] = s;
  }
  __syncthreads();
  for (int e = tid; e < 400; e += 256) {
    int i = e / 20, j = e % 20;
    float m = 0.f, pp = 0.f, qq = 0.f;
    for (int k = 0; k < 20; ++k) {
      float sk = sS[k * 20 + i];
      m += sk * sT1[k * 20 + j];
      pp += sk * P[k * 20 + j];
      qq += sk * Q[k * 20 + j];
    }
    wsc[e] = pp;
    wsc[400 + e] = -m;
    wsc[800 + e] = qq;
  }
  for (int e = tid; e < 2560; e += 256) {
    int h = e / 20, i = e % 20;
    float s = 0.f;
    for (int j = 0; j < 20; ++j) s += W2[h * 20 + j] * sS[j * 20 + i];
    wsc[2048 + e] = s;
  }
  if (tid < 32) {
    float s = 0.f;
    if (tid < 20)
      for (int j = 0; j < 20; ++j) s += b2[j] * sS[j * 20 + tid];
    wsc[1600 + tid] = s;
  }
  if (tid < NSTEP) {
    float d = ts[tid + 1] - ts[tid];
    wsc[1200 + tid] = d;
    wsc[1400 + tid] = rsqrtf(d);
  }
  __syncthreads();  // Pp/Mp/W2p visible before table build

  // ---- prepacked per-lane fragment tables (consumed verbatim by kA) ----
  unsigned* wu = (unsigned*)wsc;
  // W1F: idx = 5120 + nt*256 + l*4 + jj  (K col: 0=t, 1..20=x_j -> W1 row k0)
  for (int e = tid; e < 2048; e += 256) {
    int nt = e >> 8, rem = e & 255, l = rem >> 2, jj = rem & 3;
    int quad = l >> 4, m16 = l & 15;
    int n = nt * 16 + m16;
    int k0 = quad * 8 + 2 * jj;
    float f0 = (k0 < 21) ? W1[k0 * HID + n] : 0.f;
    float f1 = (k0 + 1 < 21) ? W1[(k0 + 1) * HID + n] : 0.f;
    wu[5120 + e] = pk2(f0, f1);
  }
  // W2F: idx = 7168 + (p*2+nt2)*256 + l*4 + jj
  for (int e = tid; e < 2048; e += 256) {
    int pnt = e >> 8, rem = e & 255, l = rem >> 2, jj = rem & 3;
    int p = pnt >> 1, nt2 = pnt & 1;
    int quad = l >> 4, m16 = l & 15;
    int n = nt2 * 16 + m16;
    bool ok = (n < 20);
    int k0 = p * 32 + quad * 8 + 2 * jj;
    float f0 = ok ? wsc[2048 + k0 * 20 + n] : 0.f;
    float f1 = ok ? wsc[2048 + (k0 + 1) * 20 + n] : 0.f;
    wu[7168 + e] = pk2(f0, f1);
  }
  // PpF: idx = 9216 + nt2*256 + l*4 + jj  -- B[k][n] for TX frag:
  //   k=0 (t col) -> 0;  k=1..20 -> Pp[n][k-1];  k>20 -> 0
  for (int e = tid; e < 512; e += 256) {
    int nt2 = e >> 8, rem = e & 255, l = rem >> 2, jj = rem & 3;
    int quad = l >> 4, m16 = l & 15;
    int n = nt2 * 16 + m16;
    bool ok = (n < 20);
    int k0 = quad * 8 + 2 * jj;
    float f0 = (ok && k0 >= 1 && k0 <= 20) ? wsc[n * 20 + (k0 - 1)] : 0.f;
    float f1 = (ok && k0 + 1 >= 1 && k0 + 1 <= 20) ? wsc[n * 20 + k0] : 0.f;
    wu[9216 + e] = pk2(f0, f1);
  }
  // MpF: idx = 9728 + nt2*256 + l*4 + jj  -- B[k][n] for Y frag:
  //   k=0..19 -> Mp[n][k];  k>=20 -> 0
  for (int e = tid; e < 512; e += 256) {
    int nt2 = e >> 8, rem = e & 255, l = rem >> 2, jj = rem & 3;
    int quad = l >> 4, m16 = l & 15;
    int n = nt2 * 16 + m16;
    bool ok = (n < 20);
    int k0 = quad * 8 + 2 * jj;
    float f0 = (ok && k0 < 20) ? wsc[400 + n * 20 + k0] : 0.f;
    float f1 = (ok && k0 + 1 < 20) ? wsc[400 + n * 20 + k0 + 1] : 0.f;
    wu[9728 + e] = pk2(f0, f1);
  }
  // B1: idx = 10240 + nt*64 + l -> b1[nt*16 + (l&15)]
  for (int e = tid; e < 512; e += 256) {
    wsc[10240 + e] = b1[(e >> 6) * 16 + (e & 15)];
  }
}

// ================= kernel A: fused MLP + integrand + chunk scan =================
// LDS is WAVE-PRIVATE only (no block barrier needed). Per-wave 3072 B:
//   tx: 16 rows x 24 bf16 (48B/row)  [t | x0..x19 | zeropad3]   @ +0
//   y : 16 rows x 32 bf16 (64B/row)  [y0..y19 | zeropad12]      @ +768 B
//   H : 16 rows x 40 bf16 (80B/row)  [h0..h31 | pad8 (unread)]  @ +1792 B
// Block total 12288 B -> LDS no longer caps occupancy.
// Weight fragments are read from GLOBAL (wsc tables, ~20KB, L2-resident) each
// step; the empty asm on wtab defeats LICM so they never become resident
// registers (round-0/4 lesson). LDS pipe per step drops from ~75 ops to ~49.
#define MFMA16(a, b, c) __builtin_amdgcn_mfma_f32_16x16x32_bf16((a), (b), (c), 0, 0, 0)

__device__ __forceinline__ short8 ldf(const float* p) {
  return *(const short8*)p;
}

// (256,5): budget ~102 regs/wave, 5 waves/SIMD. Live set ~85 (acc 24 +
// prefetch 30 + addr/temps ~30). Spill canary: FETCH_SIZE >> 96 MB.
__global__ __launch_bounds__(256, 5) void kA(
    const float* __restrict__ states, const float* __restrict__ noises,
    const float* __restrict__ controls, const float* __restrict__ ts,
    const float* __restrict__ wsc, float* __restrict__ zc,
    int nch, int cbase, int crem) {
  __shared__ __align__(16) unsigned char smem[12288];
  __hip_bfloat16* bb = (__hip_bfloat16*)smem;
  const int tid = threadIdx.x;
  const int l = tid & 63;
  const int w = tid >> 6;
  const int quad = l >> 4;
  const int m16 = l & 15;

  const int c = blockIdx.x >> 6;    // chunk; c=0 = highest t
  const int slab = blockIdx.x & 63; // 0..63
  const int b0 = slab * 64 + w * 16;
  const int sz = cbase + ((c < crem) ? 1 : 0);
  const int thi = 200 - (c * cbase + ((c < crem) ? c : crem));
  const int tlo = thi - (sz - 1);

  const int wvE = w * 1536;  // bf16-unit base of wave area (3072 B / wave)

  // ---- zero pads (wave-private; no barrier needed) ----
  if (l < 48) bb[wvE + (l / 3) * 24 + 21 + (l % 3)] = __float2bfloat16(0.f);
  for (int e = l; e < 192; e += 64)
    bb[wvE + 384 + (e / 12) * 32 + 20 + (e % 12)] = __float2bfloat16(0.f);

  float b1v[8];
#pragma unroll
  for (int nt = 0; nt < 8; ++nt) b1v[nt] = wsc[10240 + nt * 64 + l];
  const float b2pv0 = wsc[1600 + m16];
  const float b2pv1 = wsc[1616 + m16];

  // ---- invariant addresses (bf16 units) ----
  int srowT[5], srowY[5];
#pragma unroll
  for (int it = 0; it < 5; ++it) {
    int idx = it * 64 + l;
    int row = idx / 20, col = idx - row * 20;
    srowT[it] = wvE + row * 24 + 1 + col;
    srowY[it] = wvE + 384 + row * 32 + col;
  }
  const int rdTX = wvE + m16 * 24 + quad * 8;
  const int rdY = wvE + 384 + m16 * 32 + quad * 8;
  const int hE = wvE + 896;
  const int wrH = hE + quad * 4 * 40 + m16;
  const int rdH = hE + m16 * 40 + quad * 8;
  const int l4 = l << 2;  // per-lane dword offset into weight tables

  // ---- scan accumulators ----
  f32x4 A1a = {0.f, 0.f, 0.f, 0.f}, A1b = {0.f, 0.f, 0.f, 0.f};
  f32x4 A2a = {0.f, 0.f, 0.f, 0.f}, A2b = {0.f, 0.f, 0.f, 0.f};
  f32x4 La = {0.f, 0.f, 0.f, 0.f}, Lb = {0.f, 0.f, 0.f, 0.f};

  // ---- preload first t ----
  float xv[5], nv[5], cv[5];
  {
    size_t rb = ((size_t)thi * BATCH + b0) * 20;
#pragma unroll
    for (int it = 0; it < 5; ++it) {
      int idx = it * 64 + l;
      xv[it] = states[rb + idx];
      if (thi < 200) {
        nv[it] = noises[rb + idx];
        cv[it] = controls[rb + idx];
      }
    }
  }

  const float* wtab = wsc;

#pragma unroll 1
  for (int t = thi; t >= tlo; --t) {
    // opaque redefinition: keeps weight-fragment loads per-iteration
    // (blocks LICM from hoisting 20x16B of loop-invariant loads into regs)
    asm volatile("" : "+s"(wtab));

    float xn[5], nn[5], cn[5];
    if (t > tlo) {
      size_t rb = ((size_t)(t - 1) * BATCH + b0) * 20;
#pragma unroll
      for (int it = 0; it < 5; ++it) {
        int idx = it * 64 + l;
        xn[it] = states[rb + idx];
        nn[it] = noises[rb + idx];
        cn[it] = controls[rb + idx];
      }
    }
    const float tval = ts[t];
    const bool has_s = (t < 200);
    const float dtv = has_s ? wsc[1200 + t] : 0.f;
    const float rsd = has_s ? wsc[1400 + t] : 0.f;

    // ---- stage rows to LDS as bf16 (x once; y only when present) ----
#pragma unroll
    for (int it = 0; it < 5; ++it) {
      bb[srowT[it]] = __float2bfloat16(xv[it]);
      if (has_s) bb[srowY[it]] = __float2bfloat16(nv[it] * rsd + cv[it]);
    }
    if (l < 16) bb[wvE + l * 24] = __float2bfloat16(tval);

    // ---- TX fragment: one ds_read_b128 (reused by layer1 AND integrand) ----
    short8 afs;
    if (quad < 3) {
      afs = *(const short8*)&bb[rdTX];
    } else {
      S8U z; z.u[0] = z.u[1] = z.u[2] = z.u[3] = 0u;
      afs = z.s;
    }

    // ---- MLP: layer1 -> tanh(bf16 to LDS) -> layer2 (weights from L2) ----
    f32x4 u0 = {b2pv0, b2pv0, b2pv0, b2pv0};
    f32x4 u1 = {b2pv1, b2pv1, b2pv1, b2pv1};
#pragma unroll
    for (int p = 0; p < 4; ++p) {
      f32x4 aA = {b1v[2 * p], b1v[2 * p], b1v[2 * p], b1v[2 * p]};
      aA = MFMA16(afs, ldf(wtab + 5120 + (2 * p + 0) * 256 + l4), aA);
      f32x4 aB = {b1v[2 * p + 1], b1v[2 * p + 1], b1v[2 * p + 1], b1v[2 * p + 1]};
      aB = MFMA16(afs, ldf(wtab + 5120 + (2 * p + 1) * 256 + l4), aB);
#pragma unroll
      for (int reg = 0; reg < 4; ++reg) {
        bb[wrH + reg * 40] = __float2bfloat16(tanh_fast(aA[reg]));
        bb[wrH + reg * 40 + 16] = __float2bfloat16(tanh_fast(aB[reg]));
      }
      short8 hf = *(const short8*)&bb[rdH];
      u0 = MFMA16(hf, ldf(wtab + 7168 + (p * 2 + 0) * 256 + l4), u0);
      u1 = MFMA16(hf, ldf(wtab + 7168 + (p * 2 + 1) * 256 + l4), u1);
    }

    // ---- integrand s~ = TX.PpF + Y.MpF (TX frag reused) ----
    f32x4 s0 = {0.f, 0.f, 0.f, 0.f}, s1 = {0.f, 0.f, 0.f, 0.f};
    if (has_s) {
      short8 yfs = *(const short8*)&bb[rdY];
      f32x4 a0 = {0.f, 0.f, 0.f, 0.f};
      f32x4 a1 = {0.f, 0.f, 0.f, 0.f};
      a0 = MFMA16(afs, ldf(wtab + 9216 + 0 * 256 + l4), a0);
      a0 = MFMA16(yfs, ldf(wtab + 9728 + 0 * 256 + l4), a0);
      a1 = MFMA16(afs, ldf(wtab + 9216 + 1 * 256 + l4), a1);
      a1 = MFMA16(yfs, ldf(wtab + 9728 + 1 * 256 + l4), a1);
      s0 = a0 * dtv;
      s1 = a1 * dtv;
    }

    // ---- scan update ----
    La += s0;
    Lb += s1;
    f32x4 p0 = u0 - La;
    f32x4 p1 = u1 - Lb;
    A2a += p0;
    A2b += p1;
    A1a += p0 * p0;
    A1b += p1 * p1;

#pragma unroll
    for (int it = 0; it < 5; ++it) {
      xv[it] = xn[it];
      nv[it] = nn[it];
      cv[it] = cn[it];
    }
  }

  // ---- epilogue stores ----
  const size_t CH = (size_t)BATCH * DIM;
  float* zA1 = zc;
  float* zA2 = zc + (size_t)nch * CH;
  float* zS = zc + (size_t)2 * nch * CH;
  const int bb2 = b0 + quad * 4;
#pragma unroll
  for (int reg = 0; reg < 4; ++reg) {
    size_t base = ((size_t)c * BATCH + (bb2 + reg)) * 20;
    zA1[base + m16] = A1a[reg];
    zA2[base + m16] = A2a[reg];
    zS[base + m16] = La[reg];
    if (m16 < 4) {
      zA1[base + 16 + m16] = A1b[reg];
      zA2[base + 16 + m16] = A2b[reg];
      zS[base + 16 + m16] = Lb[reg];
    }
  }
}

// ================= kernel B: combine chunks =================
__global__ __launch_bounds__(256) void kB(
    const float* __restrict__ states, const float* __restrict__ lw,
    const float* __restrict__ wsc, const float* __restrict__ zc,
    float* __restrict__ out, int nch, int cbase, int crem) {
  __shared__ float sQp[400];
  __shared__ float part[4];
  int tid = threadIdx.x;
  for (int e = tid; e < 400; e += 256) sQp[e] = wsc[800 + e];
  __syncthreads();
  const int u = blockIdx.x * 256 + tid;  // < 81920
  const int b = u / 20;
  const int i = u - b * 20;
  const float* xp = states + ((size_t)NSTEP * BATCH + b) * 20;
  float term = 0.f;
#pragma unroll
  for (int j = 0; j < 20; ++j) term = fmaf(sQp[i * 20 + j], xp[j], term);

  const size_t CH = (size_t)BATCH * DIM;  // 81920
  float T = 0.f, obj = 0.f;
  for (int c = 0; c < nch; ++c) {
    float A1 = zc[(size_t)c * CH + u];
    float A2 = zc[(size_t)(nch + c) * CH + u];
    float S = zc[(size_t)(2 * nch + c) * CH + u];
    float K = term + T;
    float nc = (float)(cbase + ((c < crem) ? 1 : 0));
    obj += A1 - 2.f * K * A2 + nc * K * K;
    T += S;
  }
  obj *= __expf(lw[b]) * (1.f / ((float)TN * (float)BATCH));
#pragma unroll
  for (int off = 32; off > 0; off >>= 1) obj += __shfl_down(obj, off, 64);
  if ((tid & 63) == 0) part[tid >> 6] = obj;
  __syncthreads();
  if (tid == 0) atomicAdd(out, (part[0] + part[1]) + (part[2] + part[3]));
}

extern "C" void kernel_launch(void* const* d_in, const int* in_sizes, int n_in,
                              void* d_out, int out_size, void* d_ws, size_t ws_size,
                              hipStream_t stream) {
  const float* states = (const float*)d_in[0];
  const float* noises = (const float*)d_in[1];
  const float* controls = (const float*)d_in[2];
  const float* lw = (const float*)d_in[3];
  const float* ts = (const float*)d_in[4];
  const float* sigma = (const float*)d_in[5];
  const float* P = (const float*)d_in[6];
  const float* A = (const float*)d_in[7];
  const float* Q = (const float*)d_in[8];
  const float* W1 = (const float*)d_in[9];
  const float* b1 = (const float*)d_in[10];
  const float* W2 = (const float*)d_in[11];
  const float* b2 = (const float*)d_in[12];
  float* out = (float*)d_out;

  float* wsc = (float*)d_ws;
  float* zc = wsc + 12288;

  // nch=20 -> 1280 blocks = 5 blocks/CU (matches (256,5) budget).
  int nch = 20;
  for (;;) {
    size_t need = ((size_t)12288 + (size_t)3 * nch * BATCH * DIM) * sizeof(float);
    if (ws_size >= need || nch <= 8) break;
    nch = (nch == 20) ? 16 : (nch == 16 ? 12 : 8);
  }
  int cbase = TN / nch;
  int crem = TN - cbase * nch;

  hipMemsetAsync(out, 0, sizeof(float), stream);
  hipLaunchKernelGGL(k0_setup, dim3(1), dim3(256), 0, stream,
                     ts, sigma, A, P, Q, W2, b2, W1, b1, wsc);
  hipLaunchKernelGGL(kA, dim3(nch * 64), dim3(256), 0, stream,
                     states, noises, controls, ts, wsc, zc, nch, cbase, crem);
  hipLaunchKernelGGL(kB, dim3((BATCH * DIM) / 256), dim3(256), 0, stream,
                     states, lw, wsc, zc, out, nch, cbase, crem);
}

// Round 7
// 267.655 us; speedup vs baseline: 1.3542x; 1.3542x over previous
//
#include <hip/hip_runtime.h>
#include <hip/hip_bf16.h>
#include <math.h>

#define TN 201
#define NSTEP 200
#define BATCH 4096
#define DIM 20
#define HID 128

typedef __attribute__((ext_vector_type(8))) short short8;
typedef __attribute__((ext_vector_type(4))) float f32x4;

union S8U { short8 s; unsigned u[4]; };

__device__ __forceinline__ unsigned pk2(float lo, float hi) {
  __hip_bfloat162 h = __float22bfloat162_rn(make_float2(lo, hi));
  union { __hip_bfloat162 h; unsigned u; } v;
  v.h = h;
  return v.u;
}
__device__ __forceinline__ float tanh_fast(float x) {
  float e = __builtin_amdgcn_exp2f(x * 2.8853900817779268f);
  return 1.f - 2.f * __builtin_amdgcn_rcpf(e + 1.f);
}
// 16B load with only 4B alignment guarantee (row pitch is 80B)
__device__ __forceinline__ float4 ld4u(const float* p) {
  float4 v; __builtin_memcpy(&v, p, 16); return v;
}

// ws layout (floats):
//   [0..399]       Pp  = sigma^T P
//   [400..799]     Mp  = -sigma^T A sigma^{-T}
//   [800..1199]    Qp  = sigma^T Q
//   [1200..1399]   dt[200]
//   [1400..1599]   1/sqrt(dt)[200]
//   [1600..1631]   b2p = sigma^T b2 (padded to 32)
//   [2048..4607]   W2p = W2 sigma  [128][20]
//   [5120..7167]   W1F table: 8 frags x 64 lanes x 4 dw (prepacked bf16 pairs)
//   [7168..9215]   W2F table: 8 frags x 64 lanes x 4 dw
//   [9216..9727]   PpF table: 2 frags (TX-frag B: t-col zero, x->Pp)
//   [9728..10239]  MpF table: 2 frags (Y-frag B: y->Mp, pad zero)
//   [10240..10751] B1  table: [nt 0..7][lane 0..63]
//   [12288 ...]    zc: A1[nch][81920], A2[nch][81920], S[nch][81920]

// ================= k0: setup =================
__global__ __launch_bounds__(256) void k0_setup(
    const float* __restrict__ ts, const float* __restrict__ sigma,
    const float* __restrict__ A, const float* __restrict__ P,
    const float* __restrict__ Q, const float* __restrict__ W2,
    const float* __restrict__ b2, const float* __restrict__ W1,
    const float* __restrict__ b1, float* __restrict__ wsc) {
  __shared__ float aug[20][40];
  __shared__ float sS[400], sA[400], sT1[400];
  __shared__ float fac[20];
  int tid = threadIdx.x;
  for (int e = tid; e < 400; e += 256) { sS[e] = sigma[e]; sA[e] = A[e]; }
  for (int e = tid; e < 800; e += 256) {
    int i = e / 40, j = e % 40;
    aug[i][j] = (j < 20) ? sigma[i * 20 + j] : ((j - 20) == i ? 1.f : 0.f);
  }
  __syncthreads();
  for (int p = 0; p < 20; ++p) {
    if (tid < 64) {
      float pv = aug[p][p];
      float r = 1.f / pv;
      float rowv = 0.f, facv = 0.f;
      if (tid < 40) rowv = aug[p][tid];
      if (tid >= 40 && tid < 60) facv = aug[tid - 40][p];
      if (tid < 40) aug[p][tid] = rowv * r;
      if (tid >= 40 && tid < 60) fac[tid - 40] = facv;
    }
    __syncthreads();
    for (int e = tid; e < 800; e += 256) {
      int i = e / 40, j = e % 40;
      if (i != p) aug[i][j] -= fac[i] * aug[p][j];
    }
    __syncthreads();
  }
  // T1[k][j] = (A sigma^{-T})[k][j]
  for (int e = tid; e < 400; e += 256) {
    int k = e / 20, j = e % 20;
    float s = 0.f;
    for (int l2 = 0; l2 < 20; ++l2) s += sA[k * 20 + l2] * aug[j][20 + l2];
    sT1[e] = s;
  }
  __syncthreads();
  for (int e = tid; e < 400; e += 256) {
    int i = e / 20, j = e % 20;
    float m = 0.f, pp = 0.f, qq = 0.f;
    for (int k = 0; k < 20; ++k) {
      float sk = sS[k * 20 + i];
      m += sk * sT1[k * 20 + j];
      pp += sk * P[k * 20 + j];
      qq += sk * Q[k * 20 + j];
    }
    wsc[e] = pp;
    wsc[400 + e] = -m;
    wsc[800 + e] = qq;
  }
  for (int e = tid; e < 2560; e += 256) {
    int h = e / 20, i = e % 20;
    float s = 0.f;
    for (int j = 0; j < 20; ++j) s += W2[h * 20 + j] * sS[j * 20 + i];
    wsc[2048 + e] = s;
  }
  if (tid < 32) {
    float s = 0.f;
    if (tid < 20)
      for (int j = 0; j < 20; ++j) s += b2[j] * sS[j * 20 + tid];
    wsc[1600 + tid] = s;
  }
  if (tid < NSTEP) {
    float d = ts[tid + 1] - ts[tid];
    wsc[1200 + tid] = d;
    wsc[1400 + tid] = rsqrtf(d);
  }
  __syncthreads();

  // ---- prepacked per-lane fragment tables ----
  unsigned* wu = (unsigned*)wsc;
  // W1F (K col: 0=t, 1..20=x_j -> W1 row k0)
  for (int e = tid; e < 2048; e += 256) {
    int nt = e >> 8, rem = e & 255, l = rem >> 2, jj = rem & 3;
    int quad = l >> 4, m16 = l & 15;
    int n = nt * 16 + m16;
    int k0 = quad * 8 + 2 * jj;
    float f0 = (k0 < 21) ? W1[k0 * HID + n] : 0.f;
    float f1 = (k0 + 1 < 21) ? W1[(k0 + 1) * HID + n] : 0.f;
    wu[5120 + e] = pk2(f0, f1);
  }
  // W2F
  for (int e = tid; e < 2048; e += 256) {
    int pnt = e >> 8, rem = e & 255, l = rem >> 2, jj = rem & 3;
    int p = pnt >> 1, nt2 = pnt & 1;
    int quad = l >> 4, m16 = l & 15;
    int n = nt2 * 16 + m16;
    bool ok = (n < 20);
    int k0 = p * 32 + quad * 8 + 2 * jj;
    float f0 = ok ? wsc[2048 + k0 * 20 + n] : 0.f;
    float f1 = ok ? wsc[2048 + (k0 + 1) * 20 + n] : 0.f;
    wu[7168 + e] = pk2(f0, f1);
  }
  // PpF: B[k][n] for TX frag: k=0 -> 0; k=1..20 -> Pp[n][k-1]; k>20 -> 0
  for (int e = tid; e < 512; e += 256) {
    int nt2 = e >> 8, rem = e & 255, l = rem >> 2, jj = rem & 3;
    int quad = l >> 4, m16 = l & 15;
    int n = nt2 * 16 + m16;
    bool ok = (n < 20);
    int k0 = quad * 8 + 2 * jj;
    float f0 = (ok && k0 >= 1 && k0 <= 20) ? wsc[n * 20 + (k0 - 1)] : 0.f;
    float f1 = (ok && k0 + 1 >= 1 && k0 + 1 <= 20) ? wsc[n * 20 + k0] : 0.f;
    wu[9216 + e] = pk2(f0, f1);
  }
  // MpF: B[k][n] for Y frag: k=0..19 -> Mp[n][k]; k>=20 -> 0
  for (int e = tid; e < 512; e += 256) {
    int nt2 = e >> 8, rem = e & 255, l = rem >> 2, jj = rem & 3;
    int quad = l >> 4, m16 = l & 15;
    int n = nt2 * 16 + m16;
    bool ok = (n < 20);
    int k0 = quad * 8 + 2 * jj;
    float f0 = (ok && k0 < 20) ? wsc[400 + n * 20 + k0] : 0.f;
    float f1 = (ok && k0 + 1 < 20) ? wsc[400 + n * 20 + k0 + 1] : 0.f;
    wu[9728 + e] = pk2(f0, f1);
  }
  // B1
  for (int e = tid; e < 512; e += 256) {
    wsc[10240 + e] = b1[(e >> 6) * 16 + (e & 15)];
  }
}

// ================= kernel A =================
// LDS (bytes): H roundtrip 4 waves x 1280B @ [0,5120); tables @ 5120:
// W2F 8KB | PpF 1KB... (W2F 8 frags, PpF 2, MpF 2; 1KB each) -> total 17408 B.
// x/y MFMA fragments come STRAIGHT from global into regs (each lane loads the
// 8 contiguous dims of its batch row; 2x dword4 + 4 pk2) -- no LDS staging.
// Only the H (layer1->layer2) transpose still uses LDS (unavoidable lane perm).
#define MFMA16(a, b, c) __builtin_amdgcn_mfma_f32_16x16x32_bf16((a), (b), (c), 0, 0, 0)

// (256,3): 170-reg budget, live ~130. DO NOT tighten: (256,4)/(256,5) spilled
// (r1: FETCH 720MB, r4: 244MB, r6: 339MB). Canary: FETCH_SIZE >> 110 MB.
__global__ __launch_bounds__(256, 3) void kA(
    const float* __restrict__ states, const float* __restrict__ noises,
    const float* __restrict__ controls, const float* __restrict__ ts,
    const float* __restrict__ wsc, float* __restrict__ zc,
    int nch, int cbase, int crem) {
  __shared__ __align__(16) unsigned char smem[17408];
  __hip_bfloat16* bb = (__hip_bfloat16*)smem;
  const int tid = threadIdx.x;
  const int l = tid & 63;
  const int w = tid >> 6;
  const int quad = l >> 4;
  const int m16 = l & 15;

  const int c = blockIdx.x >> 6;
  const int slab = blockIdx.x & 63;
  const int b0 = slab * 64 + w * 16;
  const int sz = cbase + ((c < crem) ? 1 : 0);
  const int thi = 200 - (c * cbase + ((c < crem) ? c : crem));
  const int tlo = thi - (sz - 1);

  // ---- stage weight tables to LDS (12 KB, coalesced) ----
  {
    const float4* src = (const float4*)(wsc + 7168);
    float4* dst = (float4*)(smem + 5120);
    for (int e = tid; e < 768; e += 256) dst[e] = src[e];
  }

  // ---- W1 fragments in regs (8 coalesced dwordx4 from prepacked table) ----
  short8 W1f[8];
#pragma unroll
  for (int nt = 0; nt < 8; ++nt)
    W1f[nt] = *(const short8*)(wsc + 5120 + nt * 256 + l * 4);
  float b1v[8];
#pragma unroll
  for (int nt = 0; nt < 8; ++nt) b1v[nt] = wsc[10240 + nt * 64 + l];
  const float b2pv0 = wsc[1600 + m16];
  const float b2pv1 = wsc[1616 + m16];

  // ---- addresses ----
  const int hU = w * 640;                  // wave H base (bf16 units)
  const int wrH = hU + quad * 160 + m16;   // write: row=quad*4+reg, col=m16(+16)
  const int rdH = hU + m16 * 40 + quad * 8;
  const int w2l = 2560 + l * 8;            // W2F per-lane base (bf16 units)
  const int ppl = 6656 + l * 8;            // PpF
  const int mpl = 7680 + l * 8;            // MpF

  const int row20 = (b0 + m16) * 20;
  const int xoff = (quad == 0) ? 0 : ((quad == 1) ? 7 : 12);
  const int noff = (quad == 0) ? 0 : ((quad == 1) ? 8 : 12);
  const float* xb = states + row20 + xoff;
  const float* nb = noises + row20 + noff;
  const float* cb = controls + row20 + noff;

  // ---- scan accumulators ----
  f32x4 A1a = {0.f, 0.f, 0.f, 0.f}, A1b = {0.f, 0.f, 0.f, 0.f};
  f32x4 A2a = {0.f, 0.f, 0.f, 0.f}, A2b = {0.f, 0.f, 0.f, 0.f};
  f32x4 La = {0.f, 0.f, 0.f, 0.f}, Lb = {0.f, 0.f, 0.f, 0.f};

  // ---- preload first t ----
  float4 xv0, xv1, nv0 = {0, 0, 0, 0}, nv1 = {0, 0, 0, 0};
  float4 cv0 = {0, 0, 0, 0}, cv1 = {0, 0, 0, 0};
  {
    size_t rb = (size_t)thi * (BATCH * 20);
    xv0 = ld4u(xb + rb);
    xv1 = ld4u(xb + rb + 4);
    if (thi < 200) {
      nv0 = ld4u(nb + rb); nv1 = ld4u(nb + rb + 4);
      cv0 = ld4u(cb + rb); cv1 = ld4u(cb + rb + 4);
    }
  }

  __syncthreads();  // weight tables visible

#pragma unroll 1
  for (int t = thi; t >= tlo; --t) {
    float4 xn0, xn1, nn0, nn1, cn0, cn1;
    if (t > tlo) {
      size_t rb = (size_t)(t - 1) * (BATCH * 20);
      xn0 = ld4u(xb + rb); xn1 = ld4u(xb + rb + 4);
      nn0 = ld4u(nb + rb); nn1 = ld4u(nb + rb + 4);
      cn0 = ld4u(cb + rb); cn1 = ld4u(cb + rb + 4);
    }
    const float tval = ts[t];
    const bool has_s = (t < 200);
    const float dtv = has_s ? wsc[1200 + t] : 0.f;
    const float rsd = has_s ? wsc[1400 + t] : 0.f;

    // ---- TX A-fragment: packed in regs (no LDS) ----
    // lane(quad,m16) holds K cols quad*8..+7 of [t|x0..x19|pad] for row m16
    S8U af;
    if (quad == 0) {
      af.u[0] = pk2(tval, xv0.x);  af.u[1] = pk2(xv0.y, xv0.z);
      af.u[2] = pk2(xv0.w, xv1.x); af.u[3] = pk2(xv1.y, xv1.z);
    } else if (quad == 1) {        // xb = row[7..14]
      af.u[0] = pk2(xv0.x, xv0.y); af.u[1] = pk2(xv0.z, xv0.w);
      af.u[2] = pk2(xv1.x, xv1.y); af.u[3] = pk2(xv1.z, xv1.w);
    } else if (quad == 2) {        // xb = row[12..19]
      af.u[0] = pk2(xv0.w, xv1.x); af.u[1] = pk2(xv1.y, xv1.z);
      af.u[2] = pk2(xv1.w, 0.f);   af.u[3] = 0u;
    } else {
      af.u[0] = af.u[1] = af.u[2] = af.u[3] = 0u;
    }
    const short8 afs = af.s;

    // ---- MLP: layer1 (W1f regs) -> tanh -> H via LDS -> layer2 (W2F LDS) ----
    f32x4 u0 = {b2pv0, b2pv0, b2pv0, b2pv0};
    f32x4 u1 = {b2pv1, b2pv1, b2pv1, b2pv1};
#pragma unroll
    for (int p = 0; p < 4; ++p) {
      f32x4 aA = {b1v[2 * p], b1v[2 * p], b1v[2 * p], b1v[2 * p]};
      aA = MFMA16(afs, W1f[2 * p], aA);
      f32x4 aB = {b1v[2 * p + 1], b1v[2 * p + 1], b1v[2 * p + 1], b1v[2 * p + 1]};
      aB = MFMA16(afs, W1f[2 * p + 1], aB);
#pragma unroll
      for (int reg = 0; reg < 4; ++reg) {
        bb[wrH + reg * 40] = __float2bfloat16(tanh_fast(aA[reg]));
        bb[wrH + reg * 40 + 16] = __float2bfloat16(tanh_fast(aB[reg]));
      }
      short8 hf = *(const short8*)&bb[rdH];
      u0 = MFMA16(hf, *(const short8*)&bb[w2l + (p * 2 + 0) * 512], u0);
      u1 = MFMA16(hf, *(const short8*)&bb[w2l + (p * 2 + 1) * 512], u1);
    }

    // ---- integrand: s~ = TX.PpF + Y.MpF (Y packed in regs, no LDS) ----
    f32x4 s0 = {0.f, 0.f, 0.f, 0.f}, s1 = {0.f, 0.f, 0.f, 0.f};
    if (has_s) {
      S8U yf;
      if (quad <= 1) {             // nb = row[0..7] / row[8..15]
        float y0 = fmaf(nv0.x, rsd, cv0.x), y1 = fmaf(nv0.y, rsd, cv0.y);
        float y2 = fmaf(nv0.z, rsd, cv0.z), y3 = fmaf(nv0.w, rsd, cv0.w);
        float y4 = fmaf(nv1.x, rsd, cv1.x), y5 = fmaf(nv1.y, rsd, cv1.y);
        float y6 = fmaf(nv1.z, rsd, cv1.z), y7 = fmaf(nv1.w, rsd, cv1.w);
        yf.u[0] = pk2(y0, y1); yf.u[1] = pk2(y2, y3);
        yf.u[2] = pk2(y4, y5); yf.u[3] = pk2(y6, y7);
      } else if (quad == 2) {      // nb = row[12..19]; need y16..y19 = second 4
        float y0 = fmaf(nv1.x, rsd, cv1.x), y1 = fmaf(nv1.y, rsd, cv1.y);
        float y2 = fmaf(nv1.z, rsd, cv1.z), y3 = fmaf(nv1.w, rsd, cv1.w);
        yf.u[0] = pk2(y0, y1); yf.u[1] = pk2(y2, y3);
        yf.u[2] = 0u; yf.u[3] = 0u;
      } else {
        yf.u[0] = yf.u[1] = yf.u[2] = yf.u[3] = 0u;
      }
      f32x4 a0 = {0.f, 0.f, 0.f, 0.f};
      f32x4 a1 = {0.f, 0.f, 0.f, 0.f};
      a0 = MFMA16(afs, *(const short8*)&bb[ppl], a0);
      a0 = MFMA16(yf.s, *(const short8*)&bb[mpl], a0);
      a1 = MFMA16(afs, *(const short8*)&bb[ppl + 512], a1);
      a1 = MFMA16(yf.s, *(const short8*)&bb[mpl + 512], a1);
      s0 = a0 * dtv;
      s1 = a1 * dtv;
    }

    // ---- scan update ----
    La += s0;
    Lb += s1;
    f32x4 p0 = u0 - La;
    f32x4 p1 = u1 - Lb;
    A2a += p0;
    A2b += p1;
    A1a += p0 * p0;
    A1b += p1 * p1;

    // rotate prefetch
    xv0 = xn0; xv1 = xn1;
    nv0 = nn0; nv1 = nn1;
    cv0 = cn0; cv1 = cn1;
  }

  // ---- epilogue stores ----
  const size_t CH = (size_t)BATCH * DIM;
  float* zA1 = zc;
  float* zA2 = zc + (size_t)nch * CH;
  float* zS = zc + (size_t)2 * nch * CH;
  const int bb2 = b0 + quad * 4;
#pragma unroll
  for (int reg = 0; reg < 4; ++reg) {
    size_t base = ((size_t)c * BATCH + (bb2 + reg)) * 20;
    zA1[base + m16] = A1a[reg];
    zA2[base + m16] = A2a[reg];
    zS[base + m16] = La[reg];
    if (m16 < 4) {
      zA1[base + 16 + m16] = A1b[reg];
      zA2[base + 16 + m16] = A2b[reg];
      zS[base + 16 + m16] = Lb[reg];
    }
  }
}

// ================= kernel B: combine chunks =================
__global__ __launch_bounds__(256) void kB(
    const float* __restrict__ states, const float* __restrict__ lw,
    const float* __restrict__ wsc, const float* __restrict__ zc,
    float* __restrict__ out, int nch, int cbase, int crem) {
  __shared__ float sQp[400];
  __shared__ float part[4];
  int tid = threadIdx.x;
  for (int e = tid; e < 400; e += 256) sQp[e] = wsc[800 + e];
  __syncthreads();
  const int u = blockIdx.x * 256 + tid;
  const int b = u / 20;
  const int i = u - b * 20;
  const float* xp = states + ((size_t)NSTEP * BATCH + b) * 20;
  float term = 0.f;
#pragma unroll
  for (int j = 0; j < 20; ++j) term = fmaf(sQp[i * 20 + j], xp[j], term);

  const size_t CH = (size_t)BATCH * DIM;
  float T = 0.f, obj = 0.f;
  for (int c = 0; c < nch; ++c) {
    float A1 = zc[(size_t)c * CH + u];
    float A2 = zc[(size_t)(nch + c) * CH + u];
    float S = zc[(size_t)(2 * nch + c) * CH + u];
    float K = term + T;
    float nc = (float)(cbase + ((c < crem) ? 1 : 0));
    obj += A1 - 2.f * K * A2 + nc * K * K;
    T += S;
  }
  obj *= __expf(lw[b]) * (1.f / ((float)TN * (float)BATCH));
#pragma unroll
  for (int off = 32; off > 0; off >>= 1) obj += __shfl_down(obj, off, 64);
  if ((tid & 63) == 0) part[tid >> 6] = obj;
  __syncthreads();
  if (tid == 0) atomicAdd(out, (part[0] + part[1]) + (part[2] + part[3]));
}

extern "C" void kernel_launch(void* const* d_in, const int* in_sizes, int n_in,
                              void* d_out, int out_size, void* d_ws, size_t ws_size,
                              hipStream_t stream) {
  const float* states = (const float*)d_in[0];
  const float* noises = (const float*)d_in[1];
  const float* controls = (const float*)d_in[2];
  const float* lw = (const float*)d_in[3];
  const float* ts = (const float*)d_in[4];
  const float* sigma = (const float*)d_in[5];
  const float* P = (const float*)d_in[6];
  const float* A = (const float*)d_in[7];
  const float* Q = (const float*)d_in[8];
  const float* W1 = (const float*)d_in[9];
  const float* b1 = (const float*)d_in[10];
  const float* W2 = (const float*)d_in[11];
  const float* b2 = (const float*)d_in[12];
  float* out = (float*)d_out;

  float* wsc = (float*)d_ws;
  float* zc = wsc + 12288;

  // nch=12 -> 768 blocks = 3 blocks/CU (matches (256,3) budget; r3-proven ws fit)
  int nch = 12;
  size_t need = ((size_t)12288 + (size_t)3 * nch * BATCH * DIM) * sizeof(float);
  if (ws_size < need) nch = 8;
  int cbase = TN / nch;
  int crem = TN - cbase * nch;

  hipMemsetAsync(out, 0, sizeof(float), stream);
  hipLaunchKernelGGL(k0_setup, dim3(1), dim3(256), 0, stream,
                     ts, sigma, A, P, Q, W2, b2, W1, b1, wsc);
  hipLaunchKernelGGL(kA, dim3(nch * 64), dim3(256), 0, stream,
                     states, noises, controls, ts, wsc, zc, nch, cbase, crem);
  hipLaunchKernelGGL(kB, dim3((BATCH * DIM) / 256), dim3(256), 0, stream,
                     states, lw, wsc, zc, out, nch, cbase, crem);
}